// Round 3
// baseline (181.810 us; speedup 1.0000x reference)
//
#include <hip/hip_runtime.h>
#include <hip/hip_bf16.h>

// out[b, d] = remap_phase(W[labels[b], d] + noise[b, d])
// remap_phase(x) = mod(x + 1, 2) - 1   (wrap into [-1, 1))
//
// B = 262144, D = 128, N_CLASSES = 100000. fp32 data, int32 labels.
// HBM-compulsory traffic/call: noise 134MB (read) + out 134MB (write) +
// labels 1MB; W (51MB) stays L3-resident -> roofline ~43us @ 6.3TB/s.
//
// R1 was latency-bound (65.8us, 4.1TB/s, VALUBusy 6.7%): dependent
// label->W chain + runtime-trip-count loop gave ~2 outstanding loads/thread.
// Fix: compile-time ITERS, full unroll -> 8 labels, then 8 W + 8 noise
// loads all in flight. Non-temporal on the streaming noise/out traffic so
// it doesn't evict W from L2/L3.
//
// R2 compile fix: nontemporal builtins need a native vector type, not
// HIP_vector_type -> use ext_vector_type(4) float.

typedef float f32x4 __attribute__((ext_vector_type(4)));

constexpr int ITERS = 8;

__global__ void __launch_bounds__(256) label_encoder_kernel(
    const int* __restrict__ labels,
    const float* __restrict__ W,       // [N_CLASSES, 128]
    const float* __restrict__ noise,   // [B, 128]
    float* __restrict__ out,           // [B, 128]
    long long n_vec4,                  // B * 32 (float4 count)
    long long stride)                  // total threads
{
    const long long base = (long long)blockIdx.x * blockDim.x + threadIdx.x;

    long long g[ITERS];
    int lab[ITERS];
    #pragma unroll
    for (int i = 0; i < ITERS; ++i) {
        g[i] = base + (long long)i * stride;
        lab[i] = (g[i] < n_vec4) ? labels[g[i] >> 5] : 0;
    }

    f32x4 w[ITERS], nz[ITERS];
    #pragma unroll
    for (int i = 0; i < ITERS; ++i) {
        if (g[i] < n_vec4) {
            const int col4 = (int)(g[i] & 31);
            w[i] = *reinterpret_cast<const f32x4*>(
                W + (long long)lab[i] * 128 + col4 * 4);
            nz[i] = __builtin_nontemporal_load(
                reinterpret_cast<const f32x4*>(noise + g[i] * 4));
        }
    }

    #pragma unroll
    for (int i = 0; i < ITERS; ++i) {
        if (g[i] < n_vec4) {
            f32x4 r;
            #pragma unroll
            for (int j = 0; j < 4; ++j) {
                float y = w[i][j] + nz[i][j] + 1.0f;
                r[j] = y - 2.0f * floorf(y * 0.5f) - 1.0f;
            }
            __builtin_nontemporal_store(
                r, reinterpret_cast<f32x4*>(out + g[i] * 4));
        }
    }
}

extern "C" void kernel_launch(void* const* d_in, const int* in_sizes, int n_in,
                              void* d_out, int out_size, void* d_ws, size_t ws_size,
                              hipStream_t stream) {
    const int*   labels = (const int*)d_in[0];    // [B]
    const float* W      = (const float*)d_in[1];  // [N_CLASSES, 128]
    const float* noise  = (const float*)d_in[2];  // [B, 128]
    float*       out    = (float*)d_out;          // [B, 128]

    const long long n_vec4 = (long long)out_size / 4;  // 8388608

    const int block = 256;
    // exact fit: n_vec4 / (block * ITERS) = 8388608 / 2048 = 4096 blocks
    long long grid = (n_vec4 + (long long)block * ITERS - 1) /
                     ((long long)block * ITERS);
    const long long stride = grid * block;

    label_encoder_kernel<<<(int)grid, block, 0, stream>>>(
        labels, W, noise, out, n_vec4, stride);
}

// Round 4
// 134.615 us; speedup vs baseline: 1.3506x; 1.3506x over previous
//
#include <hip/hip_runtime.h>
#include <hip/hip_bf16.h>

// out[b, d] = remap_phase(W[labels[b], d] + noise[b, d])
// remap_phase(x) = mod(x + 1, 2) - 1   (wrap into [-1, 1))
//
// B = 262144, D = 128, N_CLASSES = 100000. fp32 data, int32 labels.
// Compulsory HBM/call: noise 134MB + out 134MB + labels 1MB; W (51MB)
// L3-resident -> roofline ~43us @ 6.3 TB/s.
//
// History:
//  R1: grid-stride, VGPR=8, occ 76%, 65.8us (4.1 TB/s) — latency-bound,
//      dependent label->W chain, ~2 loads in flight per thread.
//  R3: unroll x8 strided -> VGPR=208, occ 11%, 181.8us — occupancy cliff.
//  R4 (this): unroll x4, CONTIGUOUS per-thread mapping: each thread owns
//      64B of one row -> ONE label load feeds 4 W loads; 4 noise loads
//      independent. Exact-fit grid (8192*256*4 = 8388608 float4) -> no
//      bounds checks. Target VGPR <= 64 so occupancy stays high.

typedef float f32x4 __attribute__((ext_vector_type(4)));

__global__ void __launch_bounds__(256) label_encoder_kernel(
    const int* __restrict__ labels,
    const float* __restrict__ W,       // [N_CLASSES, 128]
    const float* __restrict__ noise,   // [B, 128]
    float* __restrict__ out)           // [B, 128]
{
    // thread t owns float4 indices [4t, 4t+4) = 64 bytes of one row.
    // row = t >> 3 (8 threads per 512B row), col4 = (t & 7) * 4.
    const int t = blockIdx.x * blockDim.x + threadIdx.x;

    const int lab = labels[t >> 3];    // 8-way broadcast within wave

    const f32x4* wp = reinterpret_cast<const f32x4*>(
        W + (long long)lab * 128 + (t & 7) * 16);
    const f32x4* np = reinterpret_cast<const f32x4*>(
        noise + (long long)t * 16);
    f32x4* op = reinterpret_cast<f32x4*>(out + (long long)t * 16);

    f32x4 w[4], nz[4];
    #pragma unroll
    for (int i = 0; i < 4; ++i)
        nz[i] = __builtin_nontemporal_load(np + i);
    #pragma unroll
    for (int i = 0; i < 4; ++i)
        w[i] = wp[i];

    #pragma unroll
    for (int i = 0; i < 4; ++i) {
        f32x4 r;
        #pragma unroll
        for (int j = 0; j < 4; ++j) {
            float y = w[i][j] + nz[i][j] + 1.0f;
            r[j] = y - 2.0f * floorf(y * 0.5f) - 1.0f;
        }
        __builtin_nontemporal_store(r, op + i);
    }
}

extern "C" void kernel_launch(void* const* d_in, const int* in_sizes, int n_in,
                              void* d_out, int out_size, void* d_ws, size_t ws_size,
                              hipStream_t stream) {
    const int*   labels = (const int*)d_in[0];    // [B]
    const float* W      = (const float*)d_in[1];  // [N_CLASSES, 128]
    const float* noise  = (const float*)d_in[2];  // [B, 128]
    float*       out    = (float*)d_out;          // [B, 128]

    // out_size = 33554432 floats = 8388608 float4; each thread does 4.
    const int block = 256;
    const int grid  = (int)((long long)out_size / 16 / block);  // 8192
    label_encoder_kernel<<<grid, block, 0, stream>>>(labels, W, noise, out);
}

// Round 5
// 61.493 us; speedup vs baseline: 2.9566x; 2.1891x over previous
//
#include <hip/hip_runtime.h>
#include <hip/hip_bf16.h>

// out[b, d] = remap_phase(W[labels[b], d] + noise[b, d])
// remap_phase(x) = mod(x + 1, 2) - 1   (wrap into [-1, 1))
//
// B = 262144, D = 128, N_CLASSES = 100000. fp32 data, int32 labels.
// Compulsory HBM/call: noise 134MB + out 134MB + labels 1MB; W (51MB)
// L3-resident -> roofline ~43us @ 6.3 TB/s.
//
// History:
//  R1: grid-stride, VGPR=8, occ 76%, 65.8us (4.1 TB/s) — latency-bound.
//  R3: unroll x8 strided -> VGPR=208, occ 11%, 181.8us — occupancy cliff.
//  R4: per-thread-contiguous 64B -> stores strided 64B per instruction ->
//      WRITE_SIZE 131->236MB (partial-line write amplification), 134.6us.
//  R5 (this): lane-consecutive float4 (per-instruction coalesced, like R1)
//      + ITERS=4 block-contiguous unroll (g = blk*1024 + i*256 + tid):
//      every access instruction covers 1KB contiguous; 4 label loads then
//      4 W + 4 noise loads in flight; VGPR target <= 64.

typedef float f32x4 __attribute__((ext_vector_type(4)));

constexpr int ITERS = 4;

__global__ void __launch_bounds__(256) label_encoder_kernel(
    const int* __restrict__ labels,
    const float* __restrict__ W,       // [N_CLASSES, 128]
    const float* __restrict__ noise,   // [B, 128]
    float* __restrict__ out)           // [B, 128]
{
    // block owns float4 range [blk*1024, blk*1024 + 1024) = 32 rows.
    // iteration i: g = blk*1024 + i*256 + tid -> lanes consecutive.
    const int tid = threadIdx.x;
    const int g0  = blockIdx.x * (256 * ITERS) + tid;

    int g[ITERS], lab[ITERS];
    #pragma unroll
    for (int i = 0; i < ITERS; ++i) {
        g[i] = g0 + i * 256;
        lab[i] = labels[g[i] >> 5];    // 32 lanes share a row's label
    }

    f32x4 w[ITERS], nz[ITERS];
    #pragma unroll
    for (int i = 0; i < ITERS; ++i)
        nz[i] = __builtin_nontemporal_load(
            reinterpret_cast<const f32x4*>(noise) + g[i]);
    #pragma unroll
    for (int i = 0; i < ITERS; ++i)
        w[i] = *(reinterpret_cast<const f32x4*>(W)
                 + (long long)lab[i] * 32 + (g[i] & 31));

    #pragma unroll
    for (int i = 0; i < ITERS; ++i) {
        f32x4 r;
        #pragma unroll
        for (int j = 0; j < 4; ++j) {
            float y = w[i][j] + nz[i][j] + 1.0f;
            r[j] = y - 2.0f * floorf(y * 0.5f) - 1.0f;
        }
        __builtin_nontemporal_store(
            r, reinterpret_cast<f32x4*>(out) + g[i]);
    }
}

extern "C" void kernel_launch(void* const* d_in, const int* in_sizes, int n_in,
                              void* d_out, int out_size, void* d_ws, size_t ws_size,
                              hipStream_t stream) {
    const int*   labels = (const int*)d_in[0];    // [B]
    const float* W      = (const float*)d_in[1];  // [N_CLASSES, 128]
    const float* noise  = (const float*)d_in[2];  // [B, 128]
    float*       out    = (float*)d_out;          // [B, 128]

    // out_size = 33554432 floats = 8388608 float4; 1024 float4 per block.
    const int block = 256;
    const int grid  = (int)((long long)out_size / 4 / (block * ITERS)); // 8192
    label_encoder_kernel<<<grid, block, 0, stream>>>(labels, W, noise, out);
}